// Round 1
// baseline (92675.336 us; speedup 1.0000x reference)
//
#include <hip/hip_runtime.h>
#include <cmath>

#define Bv 64
#define Lv 4
#define Hv 512
#define Tv 256
#define G4 (4*Hv)   // 2048

__device__ __forceinline__ float sigmoidf_(float x) {
    return 1.0f / (1.0f + __expf(-x));
}

// Transpose W [L][G4][H] -> Wt [L][H][G4] so k-loop W loads are lane-coalesced.
__global__ void transpose_w(const float* __restrict__ in, float* __restrict__ out) {
    __shared__ float tile[32][33];
    int l  = blockIdx.z;
    int k0 = blockIdx.x * 32;   // H dim
    int g0 = blockIdx.y * 32;   // G4 dim
    int tx = threadIdx.x, ty = threadIdx.y;  // 32 x 8
    const float* src = in  + (size_t)l * G4 * Hv;
    float*       dst = out + (size_t)l * Hv * G4;
#pragma unroll
    for (int j = 0; j < 32; j += 8)
        tile[ty + j][tx] = src[(size_t)(g0 + ty + j) * Hv + (k0 + tx)];
    __syncthreads();
#pragma unroll
    for (int j = 0; j < 32; j += 8)
        dst[(size_t)(k0 + ty + j) * G4 + (g0 + tx)] = tile[tx][ty + j];
}

// One LSTM cell (t, l): gates = x@WihT + bih + h@WhhT + bhh; update c,h.
// Thread per (b, n), computing all 4 gates for its n.
// grid: (H/64, B/4) = (8,16), block: 256 = 64 n-lanes x 4 b.
__global__ __launch_bounds__(256) void lstm_cell(
    const float* __restrict__ wt_ih, const float* __restrict__ wt_hh,
    const float* __restrict__ bih,   const float* __restrict__ bhh,
    const float* __restrict__ y,
    float* __restrict__ hbuf,  // [2][L][B][H] ping-pong by t parity
    float* __restrict__ c,     // [L][B][H]
    float* __restrict__ out,   // [B][T][H]
    int t, int l)
{
    int tid = threadIdx.x;
    int n = blockIdx.x * 64 + (tid & 63);
    int b = blockIdx.y * 4  + (tid >> 6);

    // x row: layer 0 reads previous step's top output (or y at t=0);
    // layers 1..3 read this step's h of layer l-1 (written by prior launch).
    const float* xrow;
    if (l == 0)
        xrow = (t == 0) ? (y + (size_t)b * Hv)
                        : (out + ((size_t)b * Tv + (t - 1)) * Hv);
    else
        xrow = hbuf + (((size_t)(t & 1) * Lv + (l - 1)) * Bv + b) * Hv;
    // h_old for layer l: written at step t-1 -> parity (t+1)&1 (init h0 lives in parity 1).
    const float* hrow = hbuf + (((size_t)((t + 1) & 1) * Lv + l) * Bv + b) * Hv;

    const float* wi = wt_ih + (size_t)l * Hv * G4 + n;
    const float* wh = wt_hh + (size_t)l * Hv * G4 + n;

    float ai = 0.f, af = 0.f, ag = 0.f, ao = 0.f;
#pragma unroll 4
    for (int k = 0; k < Hv; ++k) {
        float xv = xrow[k];
        float hv = hrow[k];
        const float* wik = wi + (size_t)k * G4;
        const float* whk = wh + (size_t)k * G4;
        ai = fmaf(xv, wik[0],      ai);  ai = fmaf(hv, whk[0],      ai);
        af = fmaf(xv, wik[512],    af);  af = fmaf(hv, whk[512],    af);
        ag = fmaf(xv, wik[1024],   ag);  ag = fmaf(hv, whk[1024],   ag);
        ao = fmaf(xv, wik[1536],   ao);  ao = fmaf(hv, whk[1536],   ao);
    }

    int gb = l * G4 + n;  // bias base: gate g at gb + g*512
    ai += bih[gb]         + bhh[gb];
    af += bih[gb + 512]   + bhh[gb + 512];
    ag += bih[gb + 1024]  + bhh[gb + 1024];
    ao += bih[gb + 1536]  + bhh[gb + 1536];

    float ig = sigmoidf_(ai);
    float fg = sigmoidf_(af);
    float gg = tanhf(ag);
    float og = sigmoidf_(ao);

    size_t ci = ((size_t)l * Bv + b) * Hv + n;
    float cn = fg * c[ci] + ig * gg;
    c[ci] = cn;
    float hn = og * tanhf(cn);

    hbuf[(((size_t)(t & 1) * Lv + l) * Bv + b) * Hv + n] = hn;
    if (l == Lv - 1)
        out[((size_t)b * Tv + t) * Hv + n] = hn;
}

extern "C" void kernel_launch(void* const* d_in, const int* in_sizes, int n_in,
                              void* d_out, int out_size, void* d_ws, size_t ws_size,
                              hipStream_t stream)
{
    const float* y   = (const float*)d_in[0];
    const float* h0  = (const float*)d_in[1];
    const float* c0  = (const float*)d_in[2];
    const float* Wih = (const float*)d_in[3];
    const float* Whh = (const float*)d_in[4];
    const float* bih = (const float*)d_in[5];
    const float* bhh = (const float*)d_in[6];
    // seq_len is fixed at 256 for this problem (device scalar; hardcoded Tv).
    float* out = (float*)d_out;

    // ws layout:
    //   [0,                16777216) Wt_ih   (L*H*G4*4)
    //   [16777216,         33554432) Wt_hh
    //   [33554432,         34603008) hbuf    (2*L*B*H*4 = 1 MiB)
    //   [34603008,         35127296) c       (L*B*H*4 = 512 KiB)
    char* ws = (char*)d_ws;
    float* wt_ih = (float*)ws;
    float* wt_hh = (float*)(ws + 16777216);
    float* hbuf  = (float*)(ws + 2 * 16777216);
    float* cbuf  = (float*)(ws + 2 * 16777216 + 1048576);

    dim3 tb(32, 8);
    dim3 tg(Hv / 32, G4 / 32, Lv);  // (16, 64, 4)
    transpose_w<<<tg, tb, 0, stream>>>(Wih, wt_ih);
    transpose_w<<<tg, tb, 0, stream>>>(Whh, wt_hh);

    const size_t state_bytes = (size_t)Lv * Bv * Hv * sizeof(float);
    // t=0 reads h_old from parity 1 -> put h0 there. c single-buffered.
    hipMemcpyAsync(hbuf + (size_t)Lv * Bv * Hv, h0, state_bytes,
                   hipMemcpyDeviceToDevice, stream);
    hipMemcpyAsync(cbuf, c0, state_bytes, hipMemcpyDeviceToDevice, stream);

    dim3 cb(256);
    dim3 cg(Hv / 64, Bv / 4);  // (8, 16) = 128 blocks
    for (int t = 0; t < Tv; ++t)
        for (int l = 0; l < Lv; ++l)
            lstm_cell<<<cg, cb, 0, stream>>>(wt_ih, wt_hh, bih, bhh, y,
                                             hbuf, cbuf, out, t, l);
}

// Round 2
// 43511.902 us; speedup vs baseline: 2.1299x; 2.1299x over previous
//
#include <hip/hip_runtime.h>
#include <cmath>

#define Bv 64
#define Lv 4
#define Hv 512
#define Tv 256
#define G4 (4*Hv)   // 2048

__device__ __forceinline__ float sigmoidf_(float x) {
    return 1.0f / (1.0f + __expf(-x));
}

// Build gate-interleaved transposed weights:
//   wt[l][k in 0..1023][gidx in 0..2047], gidx = 4*hn + g
//   rows k<512 from Wih[l][g*512+hn][k], rows k>=512 from Whh[l][g*512+hn][k-512]
// Block (32,8), grid (k-tiles=32, hn-tiles=16, L).
__global__ void prep_w(const float* __restrict__ Wih, const float* __restrict__ Whh,
                       float* __restrict__ wt) {
    __shared__ float tile[4][32][33];
    int l  = blockIdx.z;
    int k0 = blockIdx.x * 32;
    int h0 = blockIdx.y * 32;
    int tx = threadIdx.x, ty = threadIdx.y;  // 32 x 8
    const float* src;
    int ks;
    if (k0 < Hv) { src = Wih + (size_t)l * G4 * Hv; ks = k0; }
    else         { src = Whh + (size_t)l * G4 * Hv; ks = k0 - Hv; }
#pragma unroll
    for (int g = 0; g < 4; ++g)
#pragma unroll
        for (int j = 0; j < 32; j += 8)
            tile[g][ty + j][tx] = src[(size_t)(g * Hv + h0 + ty + j) * Hv + ks + tx];
    __syncthreads();
    // write float4 (all 4 gates of hn) : out index [(l*1024 + k)*512 + (h0+hn)] as float4
    float4* dst = (float4*)wt;
#pragma unroll
    for (int j = 0; j < 32; j += 8) {
        int k  = k0 + ty + j;
        int hn = tx;
        float4 v = make_float4(tile[0][hn][ty + j], tile[1][hn][ty + j],
                               tile[2][hn][ty + j], tile[3][hn][ty + j]);
        dst[((size_t)l * 1024 + k) * Hv + h0 + hn] = v;
    }
}

// bias_comb[l][4*hn+g] = bih[l][g*512+hn] + bhh[l][g*512+hn]
__global__ void prep_bias(const float* __restrict__ bih, const float* __restrict__ bhh,
                          float* __restrict__ bias) {
    int idx = blockIdx.x * 256 + threadIdx.x;   // 0 .. 4*2048-1
    int l = idx >> 11, g64 = idx & 2047;
    int hn = g64 >> 2, g = g64 & 3;
    bias[idx] = bih[l * G4 + g * Hv + hn] + bhh[l * G4 + g * Hv + hn];
}

// 512-length dot-product contribution for 2 interleaved gate columns,
// manual 8-deep register double-buffer so loads pipeline at 1 wave/SIMD.
__device__ __forceinline__ void dot512(const float* __restrict__ a,
                                       const float* __restrict__ w,
                                       float& acc0, float& acc1) {
    float2 wA[8], wB[8];
    float  aA[8], aB[8];
#pragma unroll
    for (int j = 0; j < 8; ++j) {
        wA[j] = *(const float2*)(w + (size_t)j * G4);
        aA[j] = a[j];
    }
    int k0 = 0;
    for (; k0 < Hv - 16; k0 += 16) {
#pragma unroll
        for (int j = 0; j < 8; ++j) {
            wB[j] = *(const float2*)(w + (size_t)(k0 + 8 + j) * G4);
            aB[j] = a[k0 + 8 + j];
        }
#pragma unroll
        for (int j = 0; j < 8; ++j) {
            acc0 = fmaf(aA[j], wA[j].x, acc0);
            acc1 = fmaf(aA[j], wA[j].y, acc1);
        }
#pragma unroll
        for (int j = 0; j < 8; ++j) {
            wA[j] = *(const float2*)(w + (size_t)(k0 + 16 + j) * G4);
            aA[j] = a[k0 + 16 + j];
        }
#pragma unroll
        for (int j = 0; j < 8; ++j) {
            acc0 = fmaf(aB[j], wB[j].x, acc0);
            acc1 = fmaf(aB[j], wB[j].y, acc1);
        }
    }
    // k0 == 496: final 16
#pragma unroll
    for (int j = 0; j < 8; ++j) {
        wB[j] = *(const float2*)(w + (size_t)(k0 + 8 + j) * G4);
        aB[j] = a[k0 + 8 + j];
    }
#pragma unroll
    for (int j = 0; j < 8; ++j) {
        acc0 = fmaf(aA[j], wA[j].x, acc0);
        acc1 = fmaf(aA[j], wA[j].y, acc1);
    }
#pragma unroll
    for (int j = 0; j < 8; ++j) {
        acc0 = fmaf(aB[j], wB[j].x, acc0);
        acc1 = fmaf(aB[j], wB[j].y, acc1);
    }
}

// One LSTM cell (t,l). Full machine: grid (32 n-tiles, 8 b-tiles) x 256 thr.
// Thread: 2 interleaved gate columns (gn0, gn0+1) for one batch b.
// Epilogue: LDS gate exchange -> fused elementwise update (threads 0..127).
__global__ __launch_bounds__(256) void lstm_cell(
    const float* __restrict__ wt, const float* __restrict__ bias,
    const float* __restrict__ y,
    float* __restrict__ hbuf,   // [2][L][B][H] ping-pong by t parity
    float* __restrict__ cbuf,   // [L][B][H]
    float* __restrict__ out,    // [B][T][H]
    int t, int l)
{
    int tid = threadIdx.x;
    int np  = tid & 31;          // n-pair
    int bi  = tid >> 5;          // 0..7
    int gn  = blockIdx.x * 64 + np * 2;   // interleaved gate index (even)
    int b   = blockIdx.y * 8 + bi;

    const float* xrow;
    if (l == 0)
        xrow = (t == 0) ? (y + (size_t)b * Hv)
                        : (out + ((size_t)b * Tv + (t - 1)) * Hv);
    else
        xrow = hbuf + (((size_t)(t & 1) * Lv + (l - 1)) * Bv + b) * Hv;
    const float* hrow = hbuf + (((size_t)((t + 1) & 1) * Lv + l) * Bv + b) * Hv;

    const float* w = wt + (size_t)l * 1024 * G4 + gn;

    float acc0 = 0.f, acc1 = 0.f;
    dot512(xrow, w, acc0, acc1);                       // x @ Wih^T rows 0..511
    dot512(hrow, w + (size_t)Hv * G4, acc0, acc1);     // h @ Whh^T rows 512..1023

    __shared__ float sg[64][9];
    sg[np * 2][bi]     = acc0;
    sg[np * 2 + 1][bi] = acc1;
    __syncthreads();

    if (tid < 128) {
        int hn_l = tid & 15;     // local h-n (16 per block)
        int bi2  = tid >> 4;     // 0..7
        float gi = sg[4 * hn_l + 0][bi2];
        float gf = sg[4 * hn_l + 1][bi2];
        float gg = sg[4 * hn_l + 2][bi2];
        float go = sg[4 * hn_l + 3][bi2];
        int gn0 = blockIdx.x * 64 + 4 * hn_l;
        const float4 bb = *(const float4*)(bias + l * G4 + gn0);
        gi += bb.x; gf += bb.y; gg += bb.z; go += bb.w;

        float ig = sigmoidf_(gi);
        float fg = sigmoidf_(gf);
        float gv = tanhf(gg);
        float og = sigmoidf_(go);

        int hn = blockIdx.x * 16 + hn_l;
        int b2 = blockIdx.y * 8 + bi2;
        size_t ci = ((size_t)l * Bv + b2) * Hv + hn;
        float cn = fg * cbuf[ci] + ig * gv;
        cbuf[ci] = cn;
        float hv = og * tanhf(cn);

        hbuf[(((size_t)(t & 1) * Lv + l) * Bv + b2) * Hv + hn] = hv;
        if (l == Lv - 1)
            out[((size_t)b2 * Tv + t) * Hv + hn] = hv;
    }
}

extern "C" void kernel_launch(void* const* d_in, const int* in_sizes, int n_in,
                              void* d_out, int out_size, void* d_ws, size_t ws_size,
                              hipStream_t stream)
{
    const float* y   = (const float*)d_in[0];
    const float* h0  = (const float*)d_in[1];
    const float* c0  = (const float*)d_in[2];
    const float* Wih = (const float*)d_in[3];
    const float* Whh = (const float*)d_in[4];
    const float* bih = (const float*)d_in[5];
    const float* bhh = (const float*)d_in[6];
    float* out = (float*)d_out;

    // ws layout:
    //   [0,        32M)  wt    (L * 1024 * 2048 * 4B, gate-interleaved)
    //   [32M,      +1M)  hbuf  (2*L*B*H*4)
    //   [33M,    +512K)  cbuf
    //   [33.5M,   +32K)  bias
    char* ws = (char*)d_ws;
    float* wt   = (float*)ws;
    float* hbuf = (float*)(ws + 33554432);
    float* cbuf = (float*)(ws + 33554432 + 1048576);
    float* bias = (float*)(ws + 33554432 + 1048576 + 524288);

    dim3 tb(32, 8);
    dim3 tg(32, 16, Lv);   // k-tiles, hn-tiles, layers
    prep_w<<<tg, tb, 0, stream>>>(Wih, Whh, wt);
    prep_bias<<<32, 256, 0, stream>>>(bih, bhh, bias);

    const size_t state_bytes = (size_t)Lv * Bv * Hv * sizeof(float);
    hipMemcpyAsync(hbuf + (size_t)Lv * Bv * Hv, h0, state_bytes,
                   hipMemcpyDeviceToDevice, stream);   // h0 -> parity 1
    hipMemcpyAsync(cbuf, c0, state_bytes, hipMemcpyDeviceToDevice, stream);

    dim3 cb(256);
    dim3 cg(32, 8);   // n-tiles x b-tiles = 256 blocks
    for (int t = 0; t < Tv; ++t)
        for (int l = 0; l < Lv; ++l)
            lstm_cell<<<cg, cb, 0, stream>>>(wt, bias, y, hbuf, cbuf, out, t, l);
}

// Round 3
// 38804.697 us; speedup vs baseline: 2.3883x; 1.1213x over previous
//
#include <hip/hip_runtime.h>
#include <cmath>

#define Bv 64
#define Lv 4
#define Hv 512
#define Tv 256
#define G4 (4*Hv)   // 2048

__device__ __forceinline__ float sigmoidf_(float x) {
    return 1.0f / (1.0f + __expf(-x));
}

// Build gate-interleaved transposed weights:
//   wt[l][k in 0..1023][gidx in 0..2047], gidx = 4*hn + g
//   rows k<512 from Wih[l][g*512+hn][k], rows k>=512 from Whh[l][g*512+hn][k-512]
__global__ void prep_w(const float* __restrict__ Wih, const float* __restrict__ Whh,
                       float* __restrict__ wt) {
    __shared__ float tile[4][32][33];
    int l  = blockIdx.z;
    int k0 = blockIdx.x * 32;
    int h0 = blockIdx.y * 32;
    int tx = threadIdx.x, ty = threadIdx.y;  // 32 x 8
    const float* src;
    int ks;
    if (k0 < Hv) { src = Wih + (size_t)l * G4 * Hv; ks = k0; }
    else         { src = Whh + (size_t)l * G4 * Hv; ks = k0 - Hv; }
#pragma unroll
    for (int g = 0; g < 4; ++g)
#pragma unroll
        for (int j = 0; j < 32; j += 8)
            tile[g][ty + j][tx] = src[(size_t)(g * Hv + h0 + ty + j) * Hv + ks + tx];
    __syncthreads();
    float4* dst = (float4*)wt;
#pragma unroll
    for (int j = 0; j < 32; j += 8) {
        int k  = k0 + ty + j;
        int hn = tx;
        float4 v = make_float4(tile[0][hn][ty + j], tile[1][hn][ty + j],
                               tile[2][hn][ty + j], tile[3][hn][ty + j]);
        dst[((size_t)l * 1024 + k) * Hv + h0 + hn] = v;
    }
}

// bias_comb[l][4*hn+g] = bih[l][g*512+hn] + bhh[l][g*512+hn]
__global__ void prep_bias(const float* __restrict__ bih, const float* __restrict__ bhh,
                          float* __restrict__ bias) {
    int idx = blockIdx.x * 256 + threadIdx.x;
    int l = idx >> 11, g64 = idx & 2047;
    int hn = g64 >> 2, g = g64 & 3;
    bias[idx] = bih[l * G4 + g * Hv + hn] + bhh[l * G4 + g * Hv + hn];
}

// 256-length dot contribution for 2 interleaved gate columns, 8-deep
// register double-buffer.
__device__ __forceinline__ void dot256(const float* __restrict__ a,
                                       const float* __restrict__ w,
                                       float& acc0, float& acc1) {
    float2 wA[8], wB[8];
    float  aA[8], aB[8];
#pragma unroll
    for (int j = 0; j < 8; ++j) {
        wA[j] = *(const float2*)(w + (size_t)j * G4);
        aA[j] = a[j];
    }
    int k0 = 0;
    for (; k0 < 256 - 16; k0 += 16) {
#pragma unroll
        for (int j = 0; j < 8; ++j) {
            wB[j] = *(const float2*)(w + (size_t)(k0 + 8 + j) * G4);
            aB[j] = a[k0 + 8 + j];
        }
#pragma unroll
        for (int j = 0; j < 8; ++j) {
            acc0 = fmaf(aA[j], wA[j].x, acc0);
            acc1 = fmaf(aA[j], wA[j].y, acc1);
        }
#pragma unroll
        for (int j = 0; j < 8; ++j) {
            wA[j] = *(const float2*)(w + (size_t)(k0 + 16 + j) * G4);
            aA[j] = a[k0 + 16 + j];
        }
#pragma unroll
        for (int j = 0; j < 8; ++j) {
            acc0 = fmaf(aB[j], wB[j].x, acc0);
            acc1 = fmaf(aB[j], wB[j].y, acc1);
        }
    }
#pragma unroll
    for (int j = 0; j < 8; ++j) {
        wB[j] = *(const float2*)(w + (size_t)(k0 + 8 + j) * G4);
        aB[j] = a[k0 + 8 + j];
    }
#pragma unroll
    for (int j = 0; j < 8; ++j) {
        acc0 = fmaf(aA[j], wA[j].x, acc0);
        acc1 = fmaf(aA[j], wA[j].y, acc1);
    }
#pragma unroll
    for (int j = 0; j < 8; ++j) {
        acc0 = fmaf(aB[j], wB[j].x, acc0);
        acc1 = fmaf(aB[j], wB[j].y, acc1);
    }
}

// One LSTM cell (t,l). Grid (32 n-tiles, 8 b-tiles) x 1024 thr = 1 block/CU,
// 4 waves/SIMD. Thread = 2 interleaved gate cols x 1 batch x 1 k-quarter.
// LDS reduce over k-quarters, then 128 epilogue threads do bias+nonlin+state.
__global__ __launch_bounds__(1024) void lstm_cell(
    const float* __restrict__ wt, const float* __restrict__ bias,
    const float* __restrict__ y,
    float* __restrict__ hbuf,   // [2][L][B][H] ping-pong by t parity
    float* __restrict__ cbuf,   // [L][B][H]
    float* __restrict__ out,    // [B][T][H]
    int t, int l)
{
    int tid = threadIdx.x;
    int np  = tid & 31;          // col-pair 0..31
    int bi  = (tid >> 5) & 7;    // 0..7
    int kq  = tid >> 8;          // k-quarter 0..3
    int gn  = blockIdx.x * 64 + np * 2;
    int b   = blockIdx.y * 8 + bi;

    const float* xrow;
    if (l == 0)
        xrow = (t == 0) ? (y + (size_t)b * Hv)
                        : (out + ((size_t)b * Tv + (t - 1)) * Hv);
    else
        xrow = hbuf + (((size_t)(t & 1) * Lv + (l - 1)) * Bv + b) * Hv;
    const float* hrow = hbuf + (((size_t)((t + 1) & 1) * Lv + l) * Bv + b) * Hv;

    // k quarters 0,1 -> x part (W rows 0..511); 2,3 -> h part (rows 512..1023)
    const float* arow = (kq < 2) ? (xrow + kq * 256) : (hrow + (kq - 2) * 256);
    const float* w = wt + (size_t)l * 1024 * G4 + (size_t)kq * 256 * G4 + gn;

    float acc0 = 0.f, acc1 = 0.f;
    dot256(arow, w, acc0, acc1);

    __shared__ float sg[4][64][9];
    sg[kq][np * 2][bi]     = acc0;
    sg[kq][np * 2 + 1][bi] = acc1;
    __syncthreads();

    if (tid < 128) {
        int hn_l = tid & 15;     // 16 h-units per block
        int bi2  = tid >> 4;     // 0..7
        float g4[4];
#pragma unroll
        for (int g = 0; g < 4; ++g) {
            float s = 0.f;
#pragma unroll
            for (int q = 0; q < 4; ++q)
                s += sg[q][4 * hn_l + g][bi2];
            g4[g] = s;
        }
        int gn0 = blockIdx.x * 64 + 4 * hn_l;
        const float4 bb = *(const float4*)(bias + l * G4 + gn0);

        float ig = sigmoidf_(g4[0] + bb.x);
        float fg = sigmoidf_(g4[1] + bb.y);
        float gv = tanhf(g4[2] + bb.z);
        float og = sigmoidf_(g4[3] + bb.w);

        int hn = blockIdx.x * 16 + hn_l;
        int b2 = blockIdx.y * 8 + bi2;
        size_t ci = ((size_t)l * Bv + b2) * Hv + hn;
        float cn = fg * cbuf[ci] + ig * gv;
        cbuf[ci] = cn;
        float hv = og * tanhf(cn);

        hbuf[(((size_t)(t & 1) * Lv + l) * Bv + b2) * Hv + hn] = hv;
        if (l == Lv - 1)
            out[((size_t)b2 * Tv + t) * Hv + hn] = hv;
    }
}

extern "C" void kernel_launch(void* const* d_in, const int* in_sizes, int n_in,
                              void* d_out, int out_size, void* d_ws, size_t ws_size,
                              hipStream_t stream)
{
    const float* y   = (const float*)d_in[0];
    const float* h0  = (const float*)d_in[1];
    const float* c0  = (const float*)d_in[2];
    const float* Wih = (const float*)d_in[3];
    const float* Whh = (const float*)d_in[4];
    const float* bih = (const float*)d_in[5];
    const float* bhh = (const float*)d_in[6];
    float* out = (float*)d_out;

    // ws: [0,32M) wt | [32M,+1M) hbuf | [+512K) cbuf | [+32K) bias
    char* ws = (char*)d_ws;
    float* wt   = (float*)ws;
    float* hbuf = (float*)(ws + 33554432);
    float* cbuf = (float*)(ws + 33554432 + 1048576);
    float* bias = (float*)(ws + 33554432 + 1048576 + 524288);

    dim3 tb(32, 8);
    dim3 tg(32, 16, Lv);
    prep_w<<<tg, tb, 0, stream>>>(Wih, Whh, wt);
    prep_bias<<<32, 256, 0, stream>>>(bih, bhh, bias);

    const size_t state_bytes = (size_t)Lv * Bv * Hv * sizeof(float);
    hipMemcpyAsync(hbuf + (size_t)Lv * Bv * Hv, h0, state_bytes,
                   hipMemcpyDeviceToDevice, stream);   // h0 -> parity 1
    hipMemcpyAsync(cbuf, c0, state_bytes, hipMemcpyDeviceToDevice, stream);

    dim3 cb(1024);
    dim3 cg(32, 8);   // 256 blocks, 1 per CU
    for (int t = 0; t < Tv; ++t)
        for (int l = 0; l < Lv; ++l)
            lstm_cell<<<cg, cb, 0, stream>>>(wt, bias, y, hbuf, cbuf, out, t, l);
}

// Round 4
// 32948.578 us; speedup vs baseline: 2.8127x; 1.1777x over previous
//
#include <hip/hip_runtime.h>
#include <cmath>

#define NBLK 256
#define NTHR 1024
#define Bv 64
#define Lv 4
#define Hv 512
#define Tv 256
#define G4 2048

// ws layout (bytes)
#define WT_OFF   0u                       // [256 blk][4 l][8 col][1024 k] f32 = 32 MB
#define HT_OFF   (33554432u)              // hT [2 par][4 l][128 k4][64 b][4] f32 = 1 MB
#define YT_OFF   (HT_OFF + 1048576u)      // yT [128][64][4] f32 = 128 KB
#define BIAS_OFF (YT_OFF + 131072u)       // biasC [4][2048] f32 = 32 KB
#define BAR_OFF  (BIAS_OFF + 32768u)      // bar8: 8 counters @ 64B stride; done @ +512

__device__ __forceinline__ float sigmoidf_(float x) {
    return 1.0f / (1.0f + __expf(-x));
}

// wt[bid][l][col][k]: col = 4*(hn&1)+g for hn = bid*2 + (col>>2);
// k<512 from Wih[l][g*512+hn][k], k>=512 from Whh[l][g*512+hn][k-512]
__global__ __launch_bounds__(256) void prep_wt(const float* __restrict__ Wih,
                                               const float* __restrict__ Whh,
                                               float* __restrict__ wt) {
    int bid = blockIdx.x, tid = threadIdx.x;
    float* dst = wt + (size_t)bid * (4 * 8 * 1024);
    int k = tid * 4;
#pragma unroll
    for (int l = 0; l < 4; ++l)
#pragma unroll
        for (int col = 0; col < 8; ++col) {
            int hn = bid * 2 + (col >> 2);
            int g  = col & 3;
            const float* src = (k < 512)
                ? (Wih + ((size_t)l * G4 + g * Hv + hn) * Hv + k)
                : (Whh + ((size_t)l * G4 + g * Hv + hn) * Hv + (k - 512));
            *(float4*)(dst + (size_t)(l * 8 + col) * 1024 + k) = *(const float4*)src;
        }
}

// biasC[l][4*hn+g] = bih[l][g*512+hn] + bhh[l][g*512+hn]
__global__ void prep_bias(const float* __restrict__ bih, const float* __restrict__ bhh,
                          float* __restrict__ biasC) {
    int idx = blockIdx.x * 256 + threadIdx.x;       // 8192
    int l = idx >> 11, gi = idx & 2047;
    int hn = gi >> 2, g = gi & 3;
    biasC[idx] = bih[l * G4 + g * Hv + hn] + bhh[l * G4 + g * Hv + hn];
}

// yT[k4][b][sub] = y[b][4*k4+sub]; hT[1][l][k4][b][sub] = h0[l][b][4*k4+sub]
__global__ void prep_act(const float* __restrict__ y, const float* __restrict__ h0,
                         float* __restrict__ yT, float* __restrict__ hT) {
    int idx = blockIdx.x * 256 + threadIdx.x;
    if (idx < 32768) {
        int k4 = idx >> 8, b = (idx >> 2) & 63, sub = idx & 3;
        yT[idx] = y[b * Hv + k4 * 4 + sub];
    } else if (idx < 32768 + 131072) {
        int r2 = idx - 32768;
        int l = r2 >> 15, r = r2 & 32767;
        int k4 = r >> 8, b = (r >> 2) & 63, sub = r & 3;
        hT[(size_t)(4 + l) * 32768 + r] = h0[((size_t)l * Bv + b) * Hv + k4 * 4 + sub];
    }
}

// Persistent kernel: 256 blocks x 1024 threads, 1024 phases (t*4+l).
// Block bid owns gate-cols 8*bid..8*bid+7 (h-units 2*bid, 2*bid+1) in ALL layers.
// Thread (b = tid&63, s = tid>>6): k-slice s*64..s*64+63 of the 1024-long dot.
// W read via wave-uniform (scalar-path) loads; activations via transposed dwordx4.
__global__ __launch_bounds__(NTHR, 4) void lstm_persist(
    const float* __restrict__ wt, const float* __restrict__ biasC,
    const float* __restrict__ yT, const float* __restrict__ c0,
    float* __restrict__ hT, float* __restrict__ out,
    int* __restrict__ bar8, int* __restrict__ done)
{
    const int bid = blockIdx.x;
    const int tid = threadIdx.x;
    const int b   = tid & 63;
    const int s   = __builtin_amdgcn_readfirstlane(tid >> 6);   // 0..15, wave-uniform

    __shared__ float4 redA[16][64];    // cols 0..3 (hn=0)
    __shared__ float4 redB[16][64];    // cols 4..7 (hn=1)
    __shared__ float  cst[4][2][64];   // c state [l][hn][b]

    if (tid < 512) {
        int l = tid >> 7, hn = (tid >> 6) & 1, bb = tid & 63;
        cst[l][hn][bb] = c0[((size_t)l * Bv + bb) * Hv + bid * 2 + hn];
    }
    __syncthreads();

    const float* wbase = wt + (size_t)bid * (4 * 8 * 1024);

    for (int p = 0; p < Tv * Lv; ++p) {
        const int t = p >> 2, l = p & 3;
        const int par = t & 1, ppar = par ^ 1;

        const float* xa = (l == 0)
            ? (t == 0 ? yT : hT + (size_t)(ppar * 4 + 3) * 32768)
            : hT + (size_t)(par * 4 + (l - 1)) * 32768;
        const float* ha = hT + (size_t)(ppar * 4 + l) * 32768;

        const float4* actq = (const float4*)((s < 8) ? xa : ha);
        const float*  wrow = wbase + (size_t)l * 8192 + s * 64;
        const int q0 = (s & 7) * 16;

        float acc0 = 0.f, acc1 = 0.f, acc2 = 0.f, acc3 = 0.f;
        float acc4 = 0.f, acc5 = 0.f, acc6 = 0.f, acc7 = 0.f;

#pragma unroll
        for (int w4 = 0; w4 < 4; ++w4) {
            float4 a0 = actq[(q0 + w4 * 4 + 0) * 64 + b];
            float4 a1 = actq[(q0 + w4 * 4 + 1) * 64 + b];
            float4 a2 = actq[(q0 + w4 * 4 + 2) * 64 + b];
            float4 a3 = actq[(q0 + w4 * 4 + 3) * 64 + b];
#pragma unroll
            for (int col = 0; col < 8; ++col) {
                const float* wp = wrow + col * 1024 + w4 * 16;
                float sum;
                sum  = wp[0]  * a0.x; sum = fmaf(wp[1],  a0.y, sum);
                sum  = fmaf(wp[2],  a0.z, sum); sum = fmaf(wp[3],  a0.w, sum);
                sum  = fmaf(wp[4],  a1.x, sum); sum = fmaf(wp[5],  a1.y, sum);
                sum  = fmaf(wp[6],  a1.z, sum); sum = fmaf(wp[7],  a1.w, sum);
                sum  = fmaf(wp[8],  a2.x, sum); sum = fmaf(wp[9],  a2.y, sum);
                sum  = fmaf(wp[10], a2.z, sum); sum = fmaf(wp[11], a2.w, sum);
                sum  = fmaf(wp[12], a3.x, sum); sum = fmaf(wp[13], a3.y, sum);
                sum  = fmaf(wp[14], a3.z, sum);
                float last = wp[15] * a3.w;
                switch (col) {
                    case 0: acc0 += sum + last; break;
                    case 1: acc1 += sum + last; break;
                    case 2: acc2 += sum + last; break;
                    case 3: acc3 += sum + last; break;
                    case 4: acc4 += sum + last; break;
                    case 5: acc5 += sum + last; break;
                    case 6: acc6 += sum + last; break;
                    case 7: acc7 += sum + last; break;
                }
            }
        }

        redA[s][b] = make_float4(acc0, acc1, acc2, acc3);
        redB[s][b] = make_float4(acc4, acc5, acc6, acc7);
        __syncthreads();

        if (tid < 128) {
            const int hn = tid >> 6;
            const float4* plane = hn ? &redB[0][0] : &redA[0][0];
            float gx = 0.f, gy = 0.f, gz = 0.f, gw = 0.f;
#pragma unroll
            for (int ss = 0; ss < 16; ++ss) {
                float4 r = plane[ss * 64 + b];
                gx += r.x; gy += r.y; gz += r.z; gw += r.w;
            }
            float4 bb4 = *(const float4*)(biasC + l * G4 + bid * 8 + hn * 4);
            float ig = sigmoidf_(gx + bb4.x);
            float fg = sigmoidf_(gy + bb4.y);
            float gv = tanhf(gz + bb4.z);
            float og = sigmoidf_(gw + bb4.w);

            float cn = fg * cst[l][hn][b] + ig * gv;
            cst[l][hn][b] = cn;
            float hv = og * tanhf(cn);

            int n = bid * 2 + hn;
            hT[(size_t)(par * 4 + l) * 32768 + ((n >> 2) * 64 + b) * 4 + (n & 3)] = hv;
            if (l == Lv - 1)
                out[((size_t)b * Tv + t) * Hv + n] = hv;
        }

        // ---- inter-block barrier (monotonic, two-level) ----
        __syncthreads();                 // all stores of this block complete (vmcnt drain)
        if (tid == 0) {
            __threadfence();             // flush XCD L2 -> coherence point
            atomicAdd(&bar8[(bid & 7) * 16], 1);
        }
        if (bid == 0) {
            if (tid < 8) {
                const int target = 32 * (p + 1);
                while (__hip_atomic_load(&bar8[tid * 16], __ATOMIC_ACQUIRE,
                                         __HIP_MEMORY_SCOPE_AGENT) < target) {}
            }
            __syncthreads();
            if (tid == 0)
                __hip_atomic_store(done, p + 1, __ATOMIC_RELEASE,
                                   __HIP_MEMORY_SCOPE_AGENT);
        }
        if (tid == 0) {
            while (__hip_atomic_load(done, __ATOMIC_ACQUIRE,
                                     __HIP_MEMORY_SCOPE_AGENT) < p + 1) {}
            __threadfence();             // invalidate stale L1/L2 lines before next reads
        }
        __syncthreads();
    }
}

extern "C" void kernel_launch(void* const* d_in, const int* in_sizes, int n_in,
                              void* d_out, int out_size, void* d_ws, size_t ws_size,
                              hipStream_t stream)
{
    const float* y   = (const float*)d_in[0];
    const float* h0  = (const float*)d_in[1];
    const float* c0  = (const float*)d_in[2];
    const float* Wih = (const float*)d_in[3];
    const float* Whh = (const float*)d_in[4];
    const float* bih = (const float*)d_in[5];
    const float* bhh = (const float*)d_in[6];
    float* out = (float*)d_out;

    char* ws = (char*)d_ws;
    float* wt    = (float*)(ws + WT_OFF);
    float* hT    = (float*)(ws + HT_OFF);
    float* yT    = (float*)(ws + YT_OFF);
    float* biasC = (float*)(ws + BIAS_OFF);
    int*   bar8  = (int*)(ws + BAR_OFF);
    int*   done  = (int*)(ws + BAR_OFF + 512);

    hipMemsetAsync(ws + BAR_OFF, 0, 1024, stream);

    prep_wt<<<NBLK, 256, 0, stream>>>(Wih, Whh, wt);
    prep_bias<<<32, 256, 0, stream>>>(bih, bhh, biasC);
    prep_act<<<(32768 + 131072) / 256, 256, 0, stream>>>(y, h0, yT, hT);

    lstm_persist<<<NBLK, NTHR, 0, stream>>>(wt, biasC, yT, c0, hT, out, bar8, done);
}

// Round 5
// 24997.849 us; speedup vs baseline: 3.7073x; 1.3181x over previous
//
#include <hip/hip_runtime.h>
#include <cmath>

#define NBLK 256
#define NTHR 1024
#define Bv 64
#define Lv 4
#define Hv 512
#define Tv 256
#define G4 2048

// ws layout (bytes)
#define WT_OFF   0u                       // [256 blk][4 l][8 col][1024 k] f32 = 32 MB
#define HT_OFF   (33554432u)              // hT [2 par][4 l][128 k4][64 b][4] f32 = 1 MB
#define YT_OFF   (HT_OFF + 1048576u)      // yT [128][64][4] f32 = 128 KB
#define BIAS_OFF (YT_OFF + 131072u)       // biasC [4][2048] f32 = 32 KB
#define BAR_OFF  (BIAS_OFF + 32768u)      // bar8: 8 counters @ 64B stride

__device__ __forceinline__ float sigmoidf_(float x) {
    return 1.0f / (1.0f + __expf(-x));
}

// wt[bid][l][col][k]: col = 4*(hn&1)+g for hn = bid*2 + (col>>2);
// k<512 from Wih[l][g*512+hn][k], k>=512 from Whh[l][g*512+hn][k-512]
__global__ __launch_bounds__(256) void prep_wt(const float* __restrict__ Wih,
                                               const float* __restrict__ Whh,
                                               float* __restrict__ wt) {
    int bid = blockIdx.x, tid = threadIdx.x;
    float* dst = wt + (size_t)bid * (4 * 8 * 1024);
    int k = tid * 4;
#pragma unroll
    for (int l = 0; l < 4; ++l)
#pragma unroll
        for (int col = 0; col < 8; ++col) {
            int hn = bid * 2 + (col >> 2);
            int g  = col & 3;
            const float* src = (k < 512)
                ? (Wih + ((size_t)l * G4 + g * Hv + hn) * Hv + k)
                : (Whh + ((size_t)l * G4 + g * Hv + hn) * Hv + (k - 512));
            *(float4*)(dst + (size_t)(l * 8 + col) * 1024 + k) = *(const float4*)src;
        }
}

// biasC[l][4*hn+g] = bih[l][g*512+hn] + bhh[l][g*512+hn]
__global__ void prep_bias(const float* __restrict__ bih, const float* __restrict__ bhh,
                          float* __restrict__ biasC) {
    int idx = blockIdx.x * 256 + threadIdx.x;       // 8192
    int l = idx >> 11, gi = idx & 2047;
    int hn = gi >> 2, g = gi & 3;
    biasC[idx] = bih[l * G4 + g * Hv + hn] + bhh[l * G4 + g * Hv + hn];
}

// yT[k4][b][sub] = y[b][4*k4+sub]; hT[1][l][k4][b][sub] = h0[l][b][4*k4+sub]
__global__ void prep_act(const float* __restrict__ y, const float* __restrict__ h0,
                         float* __restrict__ yT, float* __restrict__ hT) {
    int idx = blockIdx.x * 256 + threadIdx.x;
    if (idx < 32768) {
        int k4 = idx >> 8, b = (idx >> 2) & 63, sub = idx & 3;
        yT[idx] = y[b * Hv + k4 * 4 + sub];
    } else if (idx < 32768 + 131072) {
        int r2 = idx - 32768;
        int l = r2 >> 15, r = r2 & 32767;
        int k4 = r >> 8, b = (r >> 2) & 63, sub = r & 3;
        hT[(size_t)(4 + l) * 32768 + r] = h0[((size_t)l * Bv + b) * Hv + k4 * 4 + sub];
    }
}

// Persistent kernel: 256 blocks x 1024 threads, 1024 phases (t*4+l).
// Block bid owns gate-cols 8*bid..8*bid+7 (h-units 2*bid,2*bid+1), all layers.
// Thread (b = tid&63, s = tid>>6): k-slice s*64..s*64+63 of the 1024-long dot.
// Coherence: h exchange via relaxed agent-scope atomics (sc1, bypass L2);
// weights via plain loads (L2-resident, NEVER invalidated: no acquire fences).
__global__ __launch_bounds__(NTHR, 4) void lstm_persist(
    const float* __restrict__ wt, const float* __restrict__ biasC,
    const float* __restrict__ yT, const float* __restrict__ c0,
    float* __restrict__ hT, float* __restrict__ out,
    int* __restrict__ bar8)
{
    const int bid = blockIdx.x;
    const int tid = threadIdx.x;
    const int b   = tid & 63;
    const int s   = __builtin_amdgcn_readfirstlane(tid >> 6);   // 0..15 wave-uniform

    __shared__ float4 redA[16][64];    // cols 0..3 (hn=0)
    __shared__ float4 redB[16][64];    // cols 4..7 (hn=1)
    __shared__ float  cst[4][2][64];   // c state [l][hn][b]

    if (tid < 512) {
        int l = tid >> 7, hn = (tid >> 6) & 1, bb = tid & 63;
        cst[l][hn][bb] = c0[((size_t)l * Bv + bb) * Hv + bid * 2 + hn];
    }
    __syncthreads();

    const float* wbase = wt + (size_t)bid * 32768;

    for (int p = 0; p < Tv * Lv; ++p) {
        const int t = p >> 2, l = p & 3;
        const int par = t & 1, ppar = par ^ 1;

        const float* xa = (l == 0)
            ? (t == 0 ? yT : hT + (size_t)(ppar * 4 + 3) * 32768)
            : hT + (size_t)(par * 4 + (l - 1)) * 32768;
        const float* ha = hT + (size_t)(ppar * 4 + l) * 32768;

        // activation slice for this thread: 64 k-floats of batch b,
        // loaded as 32 x 8B relaxed agent atomics (sc1 -> coherent, L2-bypass)
        const float* act = (s < 8) ? xa : ha;
        const unsigned long long* aq =
            (const unsigned long long*)act + (size_t)(s & 7) * 2048 + b * 2;

        float av[64];
#pragma unroll
        for (int j = 0; j < 16; ++j) {
            unsigned long long lo = __hip_atomic_load(aq + (size_t)j * 128,
                                      __ATOMIC_RELAXED, __HIP_MEMORY_SCOPE_AGENT);
            unsigned long long hi = __hip_atomic_load(aq + (size_t)j * 128 + 1,
                                      __ATOMIC_RELAXED, __HIP_MEMORY_SCOPE_AGENT);
            av[4 * j + 0] = __uint_as_float((unsigned)(lo & 0xffffffffu));
            av[4 * j + 1] = __uint_as_float((unsigned)(lo >> 32));
            av[4 * j + 2] = __uint_as_float((unsigned)(hi & 0xffffffffu));
            av[4 * j + 3] = __uint_as_float((unsigned)(hi >> 32));
        }

        // W: wave-uniform scalar-path plain loads (L2-warm)
        const float* wrow = wbase + l * 8192 + s * 64;
        float acc[8];
#pragma unroll
        for (int col = 0; col < 8; ++col) {
            const float* wp = wrow + col * 1024;
            float sum = 0.f;
#pragma unroll
            for (int k = 0; k < 64; ++k)
                sum = fmaf(wp[k], av[k], sum);
            acc[col] = sum;
        }

        redA[s][b] = make_float4(acc[0], acc[1], acc[2], acc[3]);
        redB[s][b] = make_float4(acc[4], acc[5], acc[6], acc[7]);
        __syncthreads();

        if (tid < 128) {
            const int hn = tid >> 6;
            const float4* plane = hn ? &redB[0][0] : &redA[0][0];
            float gx = 0.f, gy = 0.f, gz = 0.f, gw = 0.f;
#pragma unroll
            for (int ss = 0; ss < 16; ++ss) {
                float4 r = plane[ss * 64 + b];
                gx += r.x; gy += r.y; gz += r.z; gw += r.w;
            }
            float4 bb4 = *(const float4*)(biasC + l * G4 + bid * 8 + hn * 4);
            float ig = sigmoidf_(gx + bb4.x);
            float fg = sigmoidf_(gy + bb4.y);
            float gv = tanhf(gz + bb4.z);
            float og = sigmoidf_(gw + bb4.w);

            float cn = fg * cst[l][hn][b] + ig * gv;
            cst[l][hn][b] = cn;
            float hv = og * tanhf(cn);

            int n = bid * 2 + hn;
            // coherent write-through (sc1): visible at fabric before flag add
            __hip_atomic_store(
                &hT[(size_t)(par * 4 + l) * 32768 + ((n >> 2) * 64 + b) * 4 + (n & 3)],
                hv, __ATOMIC_RELAXED, __HIP_MEMORY_SCOPE_AGENT);
            if (l == Lv - 1)
                out[((size_t)b * Tv + t) * Hv + n] = hv;
        }

        // __syncthreads drains each wave's vmem (waitcnt before s_barrier)
        __syncthreads();
        if (tid == 0)
            __hip_atomic_fetch_add(&bar8[(bid & 7) * 16], 1,
                                   __ATOMIC_RELEASE, __HIP_MEMORY_SCOPE_AGENT);
        if (tid < 8) {
            const int target = 32 * (p + 1);
            while (__hip_atomic_load(&bar8[tid * 16], __ATOMIC_RELAXED,
                                     __HIP_MEMORY_SCOPE_AGENT) < target) {}
        }
        __syncthreads();
    }
}

extern "C" void kernel_launch(void* const* d_in, const int* in_sizes, int n_in,
                              void* d_out, int out_size, void* d_ws, size_t ws_size,
                              hipStream_t stream)
{
    const float* y   = (const float*)d_in[0];
    const float* h0  = (const float*)d_in[1];
    const float* c0  = (const float*)d_in[2];
    const float* Wih = (const float*)d_in[3];
    const float* Whh = (const float*)d_in[4];
    const float* bih = (const float*)d_in[5];
    const float* bhh = (const float*)d_in[6];
    float* out = (float*)d_out;

    char* ws = (char*)d_ws;
    float* wt    = (float*)(ws + WT_OFF);
    float* hT    = (float*)(ws + HT_OFF);
    float* yT    = (float*)(ws + YT_OFF);
    float* biasC = (float*)(ws + BIAS_OFF);
    int*   bar8  = (int*)(ws + BAR_OFF);

    hipMemsetAsync(ws + BAR_OFF, 0, 1024, stream);

    prep_wt<<<NBLK, 256, 0, stream>>>(Wih, Whh, wt);
    prep_bias<<<32, 256, 0, stream>>>(bih, bhh, biasC);
    prep_act<<<(32768 + 131072) / 256, 256, 0, stream>>>(y, h0, yT, hT);

    lstm_persist<<<NBLK, NTHR, 0, stream>>>(wt, biasC, yT, c0, hT, out, bar8);
}